// Round 8
// baseline (466.076 us; speedup 1.0000x reference)
//
#include <hip/hip_runtime.h>
#include <hip/hip_bf16.h>
#include <math.h>

#define T_LEN 2048
#define RC 256
#define DIM 1024
#define VOCAB 50257
#define NT 32              // K tiles: 1024 / 32
#define SLOT 8192          // ushorts per LDS tile slot: 256 rows x 32 cols

using short8  = __attribute__((ext_vector_type(8))) short;
using f32x4   = __attribute__((ext_vector_type(4))) float;

#define VMCNT(n) asm volatile("s_waitcnt vmcnt(" #n ")" ::: "memory")
#define SCHED_FENCE() __builtin_amdgcn_sched_barrier(0)

__device__ __forceinline__ unsigned short f2bf(float f) {
    unsigned int u = __float_as_uint(f);
    u += 0x7fffu + ((u >> 16) & 1u);          // round-to-nearest-even
    return (unsigned short)(u >> 16);
}

// HW packed cvt: dst = {lo16=bf16(a), hi16=bf16(b)}, RNE
__device__ __forceinline__ unsigned int cvt_pk_bf16(float a, float b) {
    unsigned int r;
    asm volatile("v_cvt_pk_bf16_f32 %0, %1, %2" : "=v"(r) : "v"(a), "v"(b));
    return r;
}

__device__ __forceinline__ void async_load16(void* lds, const void* g) {
    __builtin_amdgcn_global_load_lds(
        (const __attribute__((address_space(1))) void*)g,
        (__attribute__((address_space(3))) void*)lds,
        16, 0, 0);
}

// ---------------- K1: MU = gather(token_to_mu_w^T, ids) + pos ----------------
__global__ __launch_bounds__(256) void mu_kernel(
    const int* __restrict__ ids, const float* __restrict__ tokw,
    const float* __restrict__ pos, float* __restrict__ mu) {
    int t = blockIdx.x, k = threadIdx.x;
    int id = ids[t];
    float v = tokw[(size_t)k * VOCAB + id] + pos[t * RC + k];
    mu[t * RC + k] = v;
}

// ---------------- K2: h_pre = gelu(MU @ w1^T + b1) ----------------
__global__ __launch_bounds__(256) void gemm1_gelu_kernel(
    const float* __restrict__ mu, const float* __restrict__ w1,
    const float* __restrict__ b1, float* __restrict__ hpre) {
    __shared__ float xs[16][RC];
    const int tg = blockIdx.x, ng = blockIdx.y, tid = threadIdx.x;
    const int t0 = tg * 16;
    {
        const float4* src = (const float4*)(mu + (size_t)t0 * RC);
        float4* dst = (float4*)&xs[0][0];
        #pragma unroll
        for (int i = 0; i < 4; ++i) dst[tid + 256 * i] = src[tid + 256 * i];
    }
    __syncthreads();
    const int d = ng * 256 + tid;
    float acc[16];
    const float bias = b1[d];
    #pragma unroll
    for (int t = 0; t < 16; ++t) acc[t] = bias;
    const float4* w1r = (const float4*)(w1 + (size_t)d * RC);
    for (int k4 = 0; k4 < RC / 4; ++k4) {
        const float4 w = w1r[k4];
        #pragma unroll
        for (int t = 0; t < 16; ++t) {
            const float4 xv = *(const float4*)&xs[t][k4 * 4];
            acc[t] += w.x * xv.x + w.y * xv.y + w.z * xv.z + w.w * xv.w;
        }
    }
    #pragma unroll
    for (int t = 0; t < 16; ++t) {
        float x = acc[t];
        float g = 0.5f * x * (1.0f + erff(x * 0.70710678118654752f));
        hpre[(size_t)(t0 + t) * DIM + d] = g;
    }
}

// ---------------- K3: LayerNorm -> bf16 h ----------------
__global__ __launch_bounds__(256) void ln_kernel(
    const float* __restrict__ hpre, const float* __restrict__ lnw,
    const float* __restrict__ lnb, unsigned short* __restrict__ h) {
    const int t = blockIdx.x, tid = threadIdx.x;
    const float4 v = ((const float4*)(hpre + (size_t)t * DIM))[tid];
    float s  = v.x + v.y + v.z + v.w;
    float ss = v.x * v.x + v.y * v.y + v.z * v.z + v.w * v.w;
    #pragma unroll
    for (int off = 32; off > 0; off >>= 1) {
        s  += __shfl_down(s, off, 64);
        ss += __shfl_down(ss, off, 64);
    }
    __shared__ float red[8];
    const int wid = tid >> 6, lane = tid & 63;
    if (lane == 0) { red[wid] = s; red[4 + wid] = ss; }
    __syncthreads();
    const float S  = red[0] + red[1] + red[2] + red[3];
    const float SS = red[4] + red[5] + red[6] + red[7];
    const float mean = S * (1.0f / DIM);
    const float var  = SS * (1.0f / DIM) - mean * mean;
    const float inv  = 1.0f / sqrtf(var + 1e-6f);
    const float4 wv = ((const float4*)lnw)[tid];
    const float4 bv = ((const float4*)lnb)[tid];
    ushort4 o;
    o.x = f2bf((v.x - mean) * inv * wv.x + bv.x);
    o.y = f2bf((v.y - mean) * inv * wv.y + bv.y);
    o.z = f2bf((v.z - mean) * inv * wv.z + bv.z);
    o.w = f2bf((v.w - mean) * inv * wv.w + bv.w);
    ((ushort4*)h)[(size_t)t * (DIM / 4) + tid] = o;
}

// ---------------- K4: w2 f32 -> bf16 (HW packed cvt) ----------------
__global__ __launch_bounds__(256) void cvt_kernel(
    const float* __restrict__ src, unsigned int* __restrict__ dst, int n8) {
    int i = blockIdx.x * 256 + threadIdx.x;
    const int stride = gridDim.x * 256;
    for (; i < n8; i += stride) {
        const float4 a = ((const float4*)src)[2 * i];
        const float4 b = ((const float4*)src)[2 * i + 1];
        uint4 o;
        o.x = cvt_pk_bf16(a.x, a.y);
        o.y = cvt_pk_bf16(a.z, a.w);
        o.z = cvt_pk_bf16(b.x, b.y);
        o.w = cvt_pk_bf16(b.z, b.w);
        ((uint4*)dst)[i] = o;
    }
}

// ---------------- K5: logits = h @ w2^T + b2 ----------------
// 256x256 block, 512 threads, 8 waves (2M x 4N), wave tile 128x64.
// BK=32, ring-3 LDS (96 KiB), distance-2 prefetch, counted vmcnt(4),
// 2 phases per K-tile: {ds_read subtile | stage half | barrier | setprio |
// 16 MFMA | barrier}.  T1 XCD swizzle, T2 XOR swizzle, T5 setprio.
__device__ __forceinline__ void stage_A512(
    const unsigned short* __restrict__ A, unsigned short* dst,
    int m0, int kt, int tid, int gsrc) {
    #pragma unroll
    for (int p = 0; p < 2; ++p) {
        const int idx = p * 512 + tid;
        const int row = idx >> 2;
        async_load16(dst + (size_t)idx * 8,
                     A + (size_t)(m0 + row) * DIM + kt * 32 + gsrc * 8);
    }
}
__device__ __forceinline__ void stage_B512(
    const unsigned short* __restrict__ B, unsigned short* dst,
    int n0, int kt, int tid, int gsrc) {
    #pragma unroll
    for (int p = 0; p < 2; ++p) {
        const int idx = p * 512 + tid;
        int row = n0 + (idx >> 2); if (row > VOCAB - 1) row = VOCAB - 1;
        async_load16(dst + (size_t)idx * 8,
                     B + (size_t)row * DIM + kt * 32 + gsrc * 8);
    }
}

__global__ __launch_bounds__(512, 2) void gemm2_kernel(
    const unsigned short* __restrict__ A, const unsigned short* __restrict__ B,
    const float* __restrict__ b2, float* __restrict__ out) {
    __shared__ unsigned short As[3 * SLOT];   // 48 KiB
    __shared__ unsigned short Bs[3 * SLOT];   // 48 KiB

    const int tid  = threadIdx.x;
    // T1: bijective XCD swizzle (gridDim.x = 1576 = 8*197), M-fastest
    const int cpx  = gridDim.x >> 3;   // 197
    const int wgid = (blockIdx.x & 7) * cpx + (blockIdx.x >> 3);
    const int m0   = (wgid & 7) << 8;
    const int n0   = (wgid >> 3) << 8;

    const int lane = tid & 63;
    const int lr   = lane & 15;
    const int lk   = lane >> 4;
    const int wid  = tid >> 6;
    const int wr   = wid >> 2;          // 0..1  (M)
    const int wc   = wid & 3;           // 0..3  (N)
    // T2 read-side swizzle (same verified involution as R2-R5)
    const int xr   = (lk ^ ((lr >> 1) & 3)) * 8;   // ushort offset within row
    const int arow0 = wr * 128 + lr;
    const int brow0 = wc * 64 + lr;
    // T2 source-side granule for linear global_load_lds dest
    const int gsrc = (tid & 3) ^ ((tid >> 3) & 3);

    f32x4 acc[8][4];
    #pragma unroll
    for (int m = 0; m < 8; ++m)
        #pragma unroll
        for (int n = 0; n < 4; ++n) acc[m][n] = {0.f, 0.f, 0.f, 0.f};

    // prologue: stage tiles 0,1 (issue order fenced -> vmcnt exact)
    stage_A512(A, As, m0, 0, tid, gsrc);
    stage_B512(B, Bs, n0, 0, tid, gsrc);
    SCHED_FENCE();
    stage_A512(A, As + SLOT, m0, 1, tid, gsrc);
    stage_B512(B, Bs + SLOT, n0, 1, tid, gsrc);
    SCHED_FENCE();
    VMCNT(4);                       // retire tile 0 (4 of 8 outstanding)
    __builtin_amdgcn_s_barrier();

    int cur = 0, st2 = 2;           // read slot (t%3), stage slot ((t+2)%3)
    #pragma unroll 1
    for (int t = 0; t < NT; ++t) {
        const unsigned short* As_t = As + cur * SLOT;
        const unsigned short* Bs_t = Bs + cur * SLOT;
        short8 af[4], af2[4], bf[4];

        // ---- phase 1: m0-3 x n0-3 ----
        #pragma unroll
        for (int m = 0; m < 4; ++m)
            af[m] = *(const short8*)(As_t + (arow0 + m * 16) * 32 + xr);
        #pragma unroll
        for (int n = 0; n < 4; ++n)
            bf[n] = *(const short8*)(Bs_t + (brow0 + n * 16) * 32 + xr);
        if (t + 2 < NT)
            stage_A512(A, As + st2 * SLOT, m0, t + 2, tid, gsrc);
        SCHED_FENCE();
        __builtin_amdgcn_s_barrier();
        __builtin_amdgcn_s_setprio(1);
        #pragma unroll
        for (int m = 0; m < 4; ++m)
            #pragma unroll
            for (int n = 0; n < 4; ++n)
                acc[m][n] = __builtin_amdgcn_mfma_f32_16x16x32_bf16(
                    af[m], bf[n], acc[m][n], 0, 0, 0);
        __builtin_amdgcn_s_setprio(0);
        SCHED_FENCE();
        __builtin_amdgcn_s_barrier();

        // ---- phase 2: m4-7 x n0-3 (reuse bf) ----
        #pragma unroll
        for (int m = 0; m < 4; ++m)
            af2[m] = *(const short8*)(As_t + (arow0 + (m + 4) * 16) * 32 + xr);
        if (t + 2 < NT)
            stage_B512(B, Bs + st2 * SLOT, n0, t + 2, tid, gsrc);
        SCHED_FENCE();
        // counted vmcnt: retire tile t+1 (read next group); keep t+2 in flight
        if (t < NT - 2) { VMCNT(4); } else { VMCNT(0); }
        __builtin_amdgcn_s_barrier();
        __builtin_amdgcn_s_setprio(1);
        #pragma unroll
        for (int m = 0; m < 4; ++m)
            #pragma unroll
            for (int n = 0; n < 4; ++n)
                acc[m + 4][n] = __builtin_amdgcn_mfma_f32_16x16x32_bf16(
                    af2[m], bf[n], acc[m + 4][n], 0, 0, 0);
        __builtin_amdgcn_s_setprio(0);
        SCHED_FENCE();
        __builtin_amdgcn_s_barrier();

        cur = (cur == 2) ? 0 : cur + 1;
        st2 = (st2 == 2) ? 0 : st2 + 1;
    }

    // epilogue: C row = frag_row + (lane>>4)*4 + j, col = lane&15
    float bias[4]; int col[4]; bool ok[4];
    #pragma unroll
    for (int n = 0; n < 4; ++n) {
        col[n] = n0 + wc * 64 + n * 16 + lr;
        ok[n]  = col[n] < VOCAB;
        bias[n] = ok[n] ? b2[col[n]] : 0.f;
    }
    #pragma unroll
    for (int m = 0; m < 8; ++m) {
        const int row = m0 + wr * 128 + m * 16 + lk * 4;
        #pragma unroll
        for (int n = 0; n < 4; ++n) {
            if (ok[n]) {
                #pragma unroll
                for (int j = 0; j < 4; ++j)
                    out[(size_t)(row + j) * VOCAB + col[n]] = acc[m][n][j] + bias[n];
            }
        }
    }
}

extern "C" void kernel_launch(void* const* d_in, const int* in_sizes, int n_in,
                              void* d_out, int out_size, void* d_ws, size_t ws_size,
                              hipStream_t stream) {
    (void)in_sizes; (void)n_in; (void)out_size; (void)ws_size;
    const int*   ids  = (const int*)d_in[0];
    const float* tokw = (const float*)d_in[1];
    const float* pos  = (const float*)d_in[2];
    const float* w1   = (const float*)d_in[3];
    const float* b1   = (const float*)d_in[4];
    const float* lnw  = (const float*)d_in[5];
    const float* lnb  = (const float*)d_in[6];
    const float* w2   = (const float*)d_in[7];
    const float* b2   = (const float*)d_in[8];

    float* logits = (float*)d_out;
    float* mu_out = logits + (size_t)T_LEN * VOCAB;            // MU output region

    unsigned short* w2b = (unsigned short*)d_ws;               // w2 bf16 (103 MB)
    unsigned short* hb  = (unsigned short*)((char*)d_ws + (size_t)VOCAB * DIM * 2);
    float* hpre = logits;   // scratch in logits region; fully overwritten by K5

    mu_kernel<<<dim3(T_LEN), dim3(256), 0, stream>>>(ids, tokw, pos, mu_out);
    gemm1_gelu_kernel<<<dim3(T_LEN / 16, DIM / 256), dim3(256), 0, stream>>>(
        mu_out, w1, b1, hpre);
    ln_kernel<<<dim3(T_LEN), dim3(256), 0, stream>>>(hpre, lnw, lnb, hb);
    cvt_kernel<<<dim3(2048), dim3(256), 0, stream>>>(
        w2, (unsigned int*)w2b, (int)((size_t)VOCAB * DIM / 8));
    const int ntiles_n = (VOCAB + 255) / 256;   // 197
    gemm2_kernel<<<dim3(8 * ntiles_n), dim3(512), 0, stream>>>(hb, w2b, b2, logits);
}

// Round 9
// 460.452 us; speedup vs baseline: 1.0122x; 1.0122x over previous
//
#include <hip/hip_runtime.h>
#include <hip/hip_bf16.h>
#include <math.h>

#define T_LEN 2048
#define RC 256
#define DIM 1024
#define VOCAB 50257
#define NT 32              // K tiles: 1024 / 32
#define SLOT 8192          // ushorts per LDS tile slot: 256 rows x 32 cols

using short8  = __attribute__((ext_vector_type(8))) short;
using f32x4   = __attribute__((ext_vector_type(4))) float;

#define VMCNT(n) asm volatile("s_waitcnt vmcnt(" #n ")" ::: "memory")
#define SCHED_FENCE() __builtin_amdgcn_sched_barrier(0)

__device__ __forceinline__ unsigned short f2bf(float f) {
    unsigned int u = __float_as_uint(f);
    u += 0x7fffu + ((u >> 16) & 1u);          // round-to-nearest-even
    return (unsigned short)(u >> 16);
}

// HW packed cvt: dst = {lo16=bf16(a), hi16=bf16(b)}, RNE
__device__ __forceinline__ unsigned int cvt_pk_bf16(float a, float b) {
    unsigned int r;
    asm volatile("v_cvt_pk_bf16_f32 %0, %1, %2" : "=v"(r) : "v"(a), "v"(b));
    return r;
}

__device__ __forceinline__ void async_load16(void* lds, const void* g) {
    __builtin_amdgcn_global_load_lds(
        (const __attribute__((address_space(1))) void*)g,
        (__attribute__((address_space(3))) void*)lds,
        16, 0, 0);
}

// ---------------- K1: MU = gather(token_to_mu_w^T, ids) + pos ----------------
__global__ __launch_bounds__(256) void mu_kernel(
    const int* __restrict__ ids, const float* __restrict__ tokw,
    const float* __restrict__ pos, float* __restrict__ mu) {
    int t = blockIdx.x, k = threadIdx.x;
    int id = ids[t];
    float v = tokw[(size_t)k * VOCAB + id] + pos[t * RC + k];
    mu[t * RC + k] = v;
}

// ---------------- K2: h_pre = gelu(MU @ w1^T + b1) ----------------
__global__ __launch_bounds__(256) void gemm1_gelu_kernel(
    const float* __restrict__ mu, const float* __restrict__ w1,
    const float* __restrict__ b1, float* __restrict__ hpre) {
    __shared__ float xs[16][RC];
    const int tg = blockIdx.x, ng = blockIdx.y, tid = threadIdx.x;
    const int t0 = tg * 16;
    {
        const float4* src = (const float4*)(mu + (size_t)t0 * RC);
        float4* dst = (float4*)&xs[0][0];
        #pragma unroll
        for (int i = 0; i < 4; ++i) dst[tid + 256 * i] = src[tid + 256 * i];
    }
    __syncthreads();
    const int d = ng * 256 + tid;
    float acc[16];
    const float bias = b1[d];
    #pragma unroll
    for (int t = 0; t < 16; ++t) acc[t] = bias;
    const float4* w1r = (const float4*)(w1 + (size_t)d * RC);
    for (int k4 = 0; k4 < RC / 4; ++k4) {
        const float4 w = w1r[k4];
        #pragma unroll
        for (int t = 0; t < 16; ++t) {
            const float4 xv = *(const float4*)&xs[t][k4 * 4];
            acc[t] += w.x * xv.x + w.y * xv.y + w.z * xv.z + w.w * xv.w;
        }
    }
    #pragma unroll
    for (int t = 0; t < 16; ++t) {
        float x = acc[t];
        float g = 0.5f * x * (1.0f + erff(x * 0.70710678118654752f));
        hpre[(size_t)(t0 + t) * DIM + d] = g;
    }
}

// ---------------- K3: LayerNorm -> bf16 h ----------------
__global__ __launch_bounds__(256) void ln_kernel(
    const float* __restrict__ hpre, const float* __restrict__ lnw,
    const float* __restrict__ lnb, unsigned short* __restrict__ h) {
    const int t = blockIdx.x, tid = threadIdx.x;
    const float4 v = ((const float4*)(hpre + (size_t)t * DIM))[tid];
    float s  = v.x + v.y + v.z + v.w;
    float ss = v.x * v.x + v.y * v.y + v.z * v.z + v.w * v.w;
    #pragma unroll
    for (int off = 32; off > 0; off >>= 1) {
        s  += __shfl_down(s, off, 64);
        ss += __shfl_down(ss, off, 64);
    }
    __shared__ float red[8];
    const int wid = tid >> 6, lane = tid & 63;
    if (lane == 0) { red[wid] = s; red[4 + wid] = ss; }
    __syncthreads();
    const float S  = red[0] + red[1] + red[2] + red[3];
    const float SS = red[4] + red[5] + red[6] + red[7];
    const float mean = S * (1.0f / DIM);
    const float var  = SS * (1.0f / DIM) - mean * mean;
    const float inv  = 1.0f / sqrtf(var + 1e-6f);
    const float4 wv = ((const float4*)lnw)[tid];
    const float4 bv = ((const float4*)lnb)[tid];
    ushort4 o;
    o.x = f2bf((v.x - mean) * inv * wv.x + bv.x);
    o.y = f2bf((v.y - mean) * inv * wv.y + bv.y);
    o.z = f2bf((v.z - mean) * inv * wv.z + bv.z);
    o.w = f2bf((v.w - mean) * inv * wv.w + bv.w);
    ((ushort4*)h)[(size_t)t * (DIM / 4) + tid] = o;
}

// ---------------- K4: w2 f32 -> bf16 (HW packed cvt) ----------------
__global__ __launch_bounds__(256) void cvt_kernel(
    const float* __restrict__ src, unsigned int* __restrict__ dst, int n8) {
    int i = blockIdx.x * 256 + threadIdx.x;
    const int stride = gridDim.x * 256;
    for (; i < n8; i += stride) {
        const float4 a = ((const float4*)src)[2 * i];
        const float4 b = ((const float4*)src)[2 * i + 1];
        uint4 o;
        o.x = cvt_pk_bf16(a.x, a.y);
        o.y = cvt_pk_bf16(a.z, a.w);
        o.z = cvt_pk_bf16(b.x, b.y);
        o.w = cvt_pk_bf16(b.z, b.w);
        ((uint4*)dst)[i] = o;
    }
}

// ---------------- K5: logits = h @ w2^T + b2 ----------------
// 256x256 block, 512 threads, 8 waves (2M x 4N), wave tile 128x64.
// BK=32, ring-3 LDS (96 KiB), distance-2 prefetch, counted vmcnt(4),
// 2 phases per K-tile: {ds_read subtile | stage half | barrier | setprio |
// 16 MFMA | barrier}.  T1 XCD swizzle, T2 XOR swizzle, T5 setprio.
__device__ __forceinline__ void stage_A512(
    const unsigned short* __restrict__ A, unsigned short* dst,
    int m0, int kt, int tid, int gsrc) {
    #pragma unroll
    for (int p = 0; p < 2; ++p) {
        const int idx = p * 512 + tid;
        const int row = idx >> 2;
        async_load16(dst + (size_t)idx * 8,
                     A + (size_t)(m0 + row) * DIM + kt * 32 + gsrc * 8);
    }
}
__device__ __forceinline__ void stage_B512(
    const unsigned short* __restrict__ B, unsigned short* dst,
    int n0, int kt, int tid, int gsrc) {
    #pragma unroll
    for (int p = 0; p < 2; ++p) {
        const int idx = p * 512 + tid;
        int row = n0 + (idx >> 2); if (row > VOCAB - 1) row = VOCAB - 1;
        async_load16(dst + (size_t)idx * 8,
                     B + (size_t)row * DIM + kt * 32 + gsrc * 8);
    }
}

__global__ __launch_bounds__(512, 2) void gemm2_kernel(
    const unsigned short* __restrict__ A, const unsigned short* __restrict__ B,
    const float* __restrict__ b2, float* __restrict__ out) {
    __shared__ unsigned short As[3 * SLOT];   // 48 KiB
    __shared__ unsigned short Bs[3 * SLOT];   // 48 KiB

    const int tid  = threadIdx.x;
    // T1: bijective XCD swizzle (gridDim.x = 1576 = 8*197), M-fastest
    const int cpx  = gridDim.x >> 3;   // 197
    const int wgid = (blockIdx.x & 7) * cpx + (blockIdx.x >> 3);
    const int m0   = (wgid & 7) << 8;
    const int n0   = (wgid >> 3) << 8;

    const int lane = tid & 63;
    const int lr   = lane & 15;
    const int lk   = lane >> 4;
    const int wid  = tid >> 6;
    const int wr   = wid >> 2;          // 0..1  (M)
    const int wc   = wid & 3;           // 0..3  (N)
    // T2 read-side swizzle (same verified involution as R2-R5)
    const int xr   = (lk ^ ((lr >> 1) & 3)) * 8;   // ushort offset within row
    const int arow0 = wr * 128 + lr;
    const int brow0 = wc * 64 + lr;
    // T2 source-side granule for linear global_load_lds dest
    const int gsrc = (tid & 3) ^ ((tid >> 3) & 3);

    f32x4 acc[8][4];
    #pragma unroll
    for (int m = 0; m < 8; ++m)
        #pragma unroll
        for (int n = 0; n < 4; ++n) acc[m][n] = {0.f, 0.f, 0.f, 0.f};

    // prologue: stage tiles 0,1 (issue order fenced -> vmcnt exact)
    stage_A512(A, As, m0, 0, tid, gsrc);
    stage_B512(B, Bs, n0, 0, tid, gsrc);
    SCHED_FENCE();
    stage_A512(A, As + SLOT, m0, 1, tid, gsrc);
    stage_B512(B, Bs + SLOT, n0, 1, tid, gsrc);
    SCHED_FENCE();
    VMCNT(4);                       // retire tile 0 (4 of 8 outstanding)
    __builtin_amdgcn_s_barrier();

    int cur = 0, st2 = 2;           // read slot (t%3), stage slot ((t+2)%3)
    #pragma unroll 1
    for (int t = 0; t < NT; ++t) {
        const unsigned short* As_t = As + cur * SLOT;
        const unsigned short* Bs_t = Bs + cur * SLOT;
        short8 af[4], af2[4], bf[4];

        // ---- phase 1: m0-3 x n0-3 ----
        #pragma unroll
        for (int m = 0; m < 4; ++m)
            af[m] = *(const short8*)(As_t + (arow0 + m * 16) * 32 + xr);
        #pragma unroll
        for (int n = 0; n < 4; ++n)
            bf[n] = *(const short8*)(Bs_t + (brow0 + n * 16) * 32 + xr);
        if (t + 2 < NT)
            stage_A512(A, As + st2 * SLOT, m0, t + 2, tid, gsrc);
        SCHED_FENCE();
        __builtin_amdgcn_s_barrier();
        __builtin_amdgcn_s_setprio(1);
        #pragma unroll
        for (int m = 0; m < 4; ++m)
            #pragma unroll
            for (int n = 0; n < 4; ++n)
                acc[m][n] = __builtin_amdgcn_mfma_f32_16x16x32_bf16(
                    af[m], bf[n], acc[m][n], 0, 0, 0);
        __builtin_amdgcn_s_setprio(0);
        SCHED_FENCE();
        __builtin_amdgcn_s_barrier();

        // ---- phase 2: m4-7 x n0-3 (reuse bf) ----
        #pragma unroll
        for (int m = 0; m < 4; ++m)
            af2[m] = *(const short8*)(As_t + (arow0 + (m + 4) * 16) * 32 + xr);
        if (t + 2 < NT)
            stage_B512(B, Bs + st2 * SLOT, n0, t + 2, tid, gsrc);
        SCHED_FENCE();
        // counted vmcnt: retire tile t+1 (read next group); keep t+2 in flight
        if (t < NT - 2) { VMCNT(4); } else { VMCNT(0); }
        __builtin_amdgcn_s_barrier();
        __builtin_amdgcn_s_setprio(1);
        #pragma unroll
        for (int m = 0; m < 4; ++m)
            #pragma unroll
            for (int n = 0; n < 4; ++n)
                acc[m + 4][n] = __builtin_amdgcn_mfma_f32_16x16x32_bf16(
                    af2[m], bf[n], acc[m + 4][n], 0, 0, 0);
        __builtin_amdgcn_s_setprio(0);
        SCHED_FENCE();
        __builtin_amdgcn_s_barrier();

        cur = (cur == 2) ? 0 : cur + 1;
        st2 = (st2 == 2) ? 0 : st2 + 1;
    }

    // epilogue: C row = frag_row + (lane>>4)*4 + j, col = lane&15
    float bias[4]; int col[4]; bool ok[4];
    #pragma unroll
    for (int n = 0; n < 4; ++n) {
        col[n] = n0 + wc * 64 + n * 16 + lr;
        ok[n]  = col[n] < VOCAB;
        bias[n] = ok[n] ? b2[col[n]] : 0.f;
    }
    #pragma unroll
    for (int m = 0; m < 8; ++m) {
        const int row = m0 + wr * 128 + m * 16 + lk * 4;
        #pragma unroll
        for (int n = 0; n < 4; ++n) {
            if (ok[n]) {
                #pragma unroll
                for (int j = 0; j < 4; ++j)
                    out[(size_t)(row + j) * VOCAB + col[n]] = acc[m][n][j] + bias[n];
            }
        }
    }
}

extern "C" void kernel_launch(void* const* d_in, const int* in_sizes, int n_in,
                              void* d_out, int out_size, void* d_ws, size_t ws_size,
                              hipStream_t stream) {
    (void)in_sizes; (void)n_in; (void)out_size; (void)ws_size;
    const int*   ids  = (const int*)d_in[0];
    const float* tokw = (const float*)d_in[1];
    const float* pos  = (const float*)d_in[2];
    const float* w1   = (const float*)d_in[3];
    const float* b1   = (const float*)d_in[4];
    const float* lnw  = (const float*)d_in[5];
    const float* lnb  = (const float*)d_in[6];
    const float* w2   = (const float*)d_in[7];
    const float* b2   = (const float*)d_in[8];

    float* logits = (float*)d_out;
    float* mu_out = logits + (size_t)T_LEN * VOCAB;            // MU output region

    unsigned short* w2b = (unsigned short*)d_ws;               // w2 bf16 (103 MB)
    unsigned short* hb  = (unsigned short*)((char*)d_ws + (size_t)VOCAB * DIM * 2);
    float* hpre = logits;   // scratch in logits region; fully overwritten by K5

    mu_kernel<<<dim3(T_LEN), dim3(256), 0, stream>>>(ids, tokw, pos, mu_out);
    gemm1_gelu_kernel<<<dim3(T_LEN / 16, DIM / 256), dim3(256), 0, stream>>>(
        mu_out, w1, b1, hpre);
    ln_kernel<<<dim3(T_LEN), dim3(256), 0, stream>>>(hpre, lnw, lnb, hb);
    cvt_kernel<<<dim3(2048), dim3(256), 0, stream>>>(
        w2, (unsigned int*)w2b, (int)((size_t)VOCAB * DIM / 8));
    const int ntiles_n = (VOCAB + 255) / 256;   // 197
    gemm2_kernel<<<dim3(8 * ntiles_n), dim3(512), 0, stream>>>(hb, w2b, b2, logits);
}